// Round 10
// baseline (135.778 us; speedup 1.0000x reference)
//
#include <hip/hip_runtime.h>
#include <stdint.h>

#define EPS_F 1e-7f

typedef float f32x4 __attribute__((ext_vector_type(4)));
typedef int   v8i   __attribute__((ext_vector_type(8)));

// 8 consecutive VGPRs: two b128 loads land directly in the MFMA operand tuple.
union A32 { uint4 u4[2]; v8i v; };

__device__ __forceinline__ unsigned cvt4(float a, float b, float c, float d) {
  int v = __builtin_amdgcn_cvt_pk_fp8_f32(a, b, 0, false);   // bytes 0,1
  return (unsigned)__builtin_amdgcn_cvt_pk_fp8_f32(c, d, v, true);  // bytes 2,3
}

// MX-scaled fp8 MFMA, K=128, scales = 1.0 (e8m0 127 in every byte -> opsel-proof).
#define MFMA128(A, B, C) __builtin_amdgcn_mfma_scale_f32_16x16x128_f8f6f4( \
    (A), (B), (C), 0, 0, 0, 0x7F7F7F7F, 0, 0x7F7F7F7F)

// ---------------------------------------------------------------------------
// Shared software k-order for BOTH operand images (R5-R9 verified, absmax 0):
//   fragment lane = kg*16 + (row|col)&15,  kg = lane>>4
//   nominal k  = kb*128 + kg*32 + j,  j in [0,32)
//   j in [0,16)  -> LO plane,  j in [16,32) -> HI plane
// B image: run index ri = (g*4 + kb)*64 + lane, planes of 512 KB each.
// ---------------------------------------------------------------------------

// ---------------------------------------------------------------------------
// prep: protos fp32 (2048x512) -> fp8 e4m3 B image (unchanged from R5).
// ---------------------------------------------------------------------------
__global__ __launch_bounds__(256) void prep_kernel(
    const float* __restrict__ protos, uint8_t* __restrict__ wsB,
    float* __restrict__ y2a, float* __restrict__ rya,
    float* __restrict__ out) {
  const int lane = threadIdx.x & 63;
  const int w    = threadIdx.x >> 6;
  const int c    = blockIdx.x * 4 + w;
  const int g    = c >> 4, cl = c & 15;
  const float4* p = (const float4*)(protos + (size_t)c * 512 + lane * 8);
  float4 f0 = p[0], f1 = p[1];
  float s = f0.x*f0.x + f0.y*f0.y + f0.z*f0.z + f0.w*f0.w
          + f1.x*f1.x + f1.y*f1.y + f1.z*f1.z + f1.w*f1.w;
#pragma unroll
  for (int off = 32; off > 0; off >>= 1) s += __shfl_xor(s, off, 64);
  if (lane == 0) { y2a[c] = s; rya[c] = 1.f / (1.f - s); }
  unsigned ux = cvt4(f0.x, f0.y, f0.z, f0.w);   // k [8l, 8l+4)
  unsigned uy = cvt4(f1.x, f1.y, f1.z, f1.w);   // k [8l+4, 8l+8)
  const int kb = lane >> 4, kg = (lane >> 2) & 3, bo = lane & 3;
  size_t ri  = (size_t)(g * 4 + kb) * 64 + kg * 16 + cl;
  size_t off = ri * 16 + (size_t)(bo & 1) * 8 + (size_t)(bo >> 1) * (512u * 1024u);
  *(uint2*)(wsB + off) = make_uint2(ux, uy);
  if (blockIdx.x == 0 && threadIdx.x == 0) out[0] = 0.f;
}

// ---------------------------------------------------------------------------
// gemm_min v10: 128-ROW TILES — HALVE B TRAFFIC.  256 blocks x 256 thr
// (4 waves), launch_bounds(256,1) -> VGPR cap 256 (R5/R8: no spill).
// ROUND-9 DIAGNOSIS: five structural variants (R5-R9) all pin at 60-70 us;
// the invariant is B-read traffic: 512 blocks x 1 MB = 512 MB from L2/L3,
// and B-bytes/duration converges to 6.7-8.5 TB/s in EVERY round (R0 6.7,
// R5 7.3, R6 8.1, R7/R9 8.5) -> shared-cache BW ceiling ~8.5 TB/s is the
// binding resource.  Loop structure never mattered because it never changed
// B bytes.  Fix: 128 rows/block -> each B fragment feeds 16 MFMAs (was 8)
// -> B demand 256 MB -> ~30 us at the same ceiling.
//   - grid 256 = 1 block/CU, 1 wave/SIMD; per-SIMD critical path = 1024
//     MFMA x 34.5 cyc = 14.7 us.  Per kb-step: 16 ds_read_b128 + 16
//     MFMA(K=128) + 4 global b128 (B depth-2: lookahead 2 x 552 = 1104 cyc
//     > 900-cyc L3 worst case -> a lone wave covers B latency).
//   - A: 128 x 512 fp8 = 64 KB LDS, staged via R9's verified coalesced
//     transpose (32 rows/wave, 16 super-steps); x2 fp32-exact inline.
//   - register ledger: Bp 32 + acc 64 + x2r 32 + tmin 32 + temps ~50 =
//     ~210 < 256.  WRITE_SIZE in MB => spill => abort this line.
//   - epilogue unchanged (2 col-frags per s-iter); minbuf covers 128 rows;
//     final fold by waves 0,1.
// ---------------------------------------------------------------------------
__global__ __launch_bounds__(256, 1) void gemm_min_kernel(
    const float* __restrict__ z, const uint8_t* __restrict__ wsB,
    const float* __restrict__ y2a, const float* __restrict__ rya,
    const float* __restrict__ marg, float* __restrict__ out) {
  __shared__ uint4 As2[4096];    // [pl*2048 + (kb*8+rf)*64 + kg*16 + r15]  64 KB
  __shared__ float x2s[128];
  __shared__ float rxs[128];
  __shared__ float minbuf[128][4];

  const int tid  = threadIdx.x;
  const int lane = tid & 63;
  const int w    = tid >> 6;          // wave 0..3
  const int q    = lane >> 4;         // kg / acc row-group
  const int l15  = lane & 15;
  const size_t rowbase = (size_t)blockIdx.x * 128;

  const uint4* BLo = (const uint4*)wsB;
  const uint4* BHi = BLo + 32768;     // +512 KB

  // ---- B warm-up (steps i=0,1): wave w owns cols [w*512,+512) ----
  // frag pair g0 = w*32 + 2s, g1 = g0+1; step i = s*4 + kb; slot = i&1.
  A32 Bp0[2], Bp1[2];
#pragma unroll
  for (int i = 0; i < 2; ++i) {
    size_t r0 = (size_t)(w * 128 + i) * 64 + lane;
    Bp0[i].u4[0] = BLo[r0];       Bp0[i].u4[1] = BHi[r0];
    Bp1[i].u4[0] = BLo[r0 + 256]; Bp1[i].u4[1] = BHi[r0 + 256];
  }

  // ---- A staging, coalesced (R9-verified transpose): wave w owns rows
  // [w*32, w*32+32), two rows per super-step ss = 0..15.  Each load is a
  // contiguous 1 KB wave-burst; 4-lane shfl_xor 4x4 transpose assembles
  // granules; per-row x2 reduced fp32-exact inline.
  {
    const int c4 = lane & 3;
    const int m  = lane >> 2;           // 0..15
    const float* zb = z + (rowbase + w * 32) * 512 + lane * 4;
#pragma unroll
    for (int ss = 0; ss < 16; ++ss) {
      float4 f0 = *(const float4*)(zb + (2 * ss + 0) * 512);
      float4 f1 = *(const float4*)(zb + (2 * ss + 0) * 512 + 256);
      float4 f2 = *(const float4*)(zb + (2 * ss + 1) * 512);
      float4 f3 = *(const float4*)(zb + (2 * ss + 1) * 512 + 256);
      float sa = f0.x*f0.x + f0.y*f0.y + f0.z*f0.z + f0.w*f0.w
               + f1.x*f1.x + f1.y*f1.y + f1.z*f1.z + f1.w*f1.w;
      float sb = f2.x*f2.x + f2.y*f2.y + f2.z*f2.z + f2.w*f2.w
               + f3.x*f3.x + f3.y*f3.y + f3.z*f3.z + f3.w*f3.w;
#pragma unroll
      for (int off = 32; off > 0; off >>= 1) {
        sa += __shfl_xor(sa, off, 64);
        sb += __shfl_xor(sb, off, 64);
      }
      if (lane == 0) {
        int r0 = w * 32 + 2 * ss;
        x2s[r0] = sa;     rxs[r0] = 1.f / (1.f - sa);
        x2s[r0 + 1] = sb; rxs[r0 + 1] = 1.f / (1.f - sb);
      }
      unsigned v0 = cvt4(f0.x, f0.y, f0.z, f0.w);
      unsigned v1 = cvt4(f1.x, f1.y, f1.z, f1.w);
      unsigned v2 = cvt4(f2.x, f2.y, f2.z, f2.w);
      unsigned v3 = cvt4(f3.x, f3.y, f3.z, f3.w);
      unsigned t;
      // stage A (xor 1): swap index-bit0 <-> lane-bit0
      t = (unsigned)__shfl_xor((int)((c4 & 1) ? v0 : v1), 1, 64);
      if (c4 & 1) v0 = t; else v1 = t;
      t = (unsigned)__shfl_xor((int)((c4 & 1) ? v2 : v3), 1, 64);
      if (c4 & 1) v2 = t; else v3 = t;
      // stage B (xor 2): swap index-bit1 <-> lane-bit1
      t = (unsigned)__shfl_xor((int)((c4 & 2) ? v0 : v2), 2, 64);
      if (c4 & 2) v0 = t; else v2 = t;
      t = (unsigned)__shfl_xor((int)((c4 & 2) ? v1 : v3), 2, 64);
      if (c4 & 2) v1 = t; else v3 = t;
      // lane holds granule: row-in-tile rr = w*32 + 2ss + (c4>>1),
      // K = 256*(c4&1) + 16*m, bytes [K, K+16) ascending.
      int K   = ((c4 & 1) << 8) + (m << 4);
      int kb  = K >> 7;
      int kg  = (K >> 5) & 3;
      int pl  = (K >> 4) & 1;
      int rr  = 2 * ss + (c4 >> 1);          // 0..31 within wave
      int rf  = 2 * w + (rr >> 4);           // 0..7
      int r15 = rr & 15;
      int ri  = pl * 2048 + (kb * 8 + rf) * 64 + kg * 16 + r15;
      As2[ri] = make_uint4(v0, v1, v2, v3);
    }
  }
  __syncthreads();  // the ONLY barrier before the final reduction

  // x2 resident per lane: rows rf*16 + q*4 + r
  float x2r[8][4];
#pragma unroll
  for (int rf = 0; rf < 8; ++rf) {
    float4 x4 = *(const float4*)&x2s[rf * 16 + q * 4];
    x2r[rf][0] = x4.x; x2r[rf][1] = x4.y; x2r[rf][2] = x4.z; x2r[rf][3] = x4.w;
  }

  float tmin[8][4];
#pragma unroll
  for (int rf = 0; rf < 8; ++rf)
#pragma unroll
    for (int r = 0; r < 4; ++r) tmin[rf][r] = 3.4e38f;

  const float* y2p = y2a + w * 512 + l15;
  const float* ryp = rya + w * 512 + l15;

#pragma clang loop unroll(disable)
  for (int s = 0; s < 16; ++s) {
    f32x4 acc[8][2];
#pragma unroll
    for (int rf = 0; rf < 8; ++rf) {
      f32x4 z4 = {0.f, 0.f, 0.f, 0.f};
      acc[rf][0] = z4; acc[rf][1] = z4;
    }
    float y2v0 = y2p[s * 32],      ryv0 = ryp[s * 32];
    float y2v1 = y2p[s * 32 + 16], ryv1 = ryp[s * 32 + 16];

#pragma unroll
    for (int kb = 0; kb < 4; ++kb) {
      v8i bv0 = Bp0[kb & 1].v;
      v8i bv1 = Bp1[kb & 1].v;
      {  // prefetch step i+2 into the just-consumed slot (pad absorbs tail)
        int ip = s * 4 + kb + 2;
        size_t r0 = (size_t)(w * 128 + (ip >> 2) * 8 + (ip & 3)) * 64 + lane;
        Bp0[kb & 1].u4[0] = BLo[r0];       Bp0[kb & 1].u4[1] = BHi[r0];
        Bp1[kb & 1].u4[0] = BLo[r0 + 256]; Bp1[kb & 1].u4[1] = BHi[r0 + 256];
      }
#pragma unroll
      for (int rf = 0; rf < 8; ++rf) {
        A32 a;
        int ri = (kb * 8 + rf) * 64 + lane;
        a.u4[0] = As2[ri];
        a.u4[1] = As2[2048 + ri];
        acc[rf][0] = MFMA128(a.v, bv0, acc[rf][0]);
        acc[rf][1] = MFMA128(a.v, bv1, acc[rf][1]);
      }
    }

    // epilogue: cols c0 = w*512 + s*32 + l15, c1 = c0 + 16
#pragma unroll
    for (int rf = 0; rf < 8; ++rf) {
#pragma unroll
      for (int r = 0; r < 4; ++r) {
        float xv = x2r[rf][r];
        float u0 = fmaxf(fmaf(-2.f, acc[rf][0][r], xv + y2v0), 0.f) * ryv0;
        float u1 = fmaxf(fmaf(-2.f, acc[rf][1][r], xv + y2v1), 0.f) * ryv1;
        tmin[rf][r] = fminf(tmin[rf][r], fminf(u0, u1));
      }
    }
  }

  // ---- min across the 16 lanes (l15) sharing each row ----
#pragma unroll
  for (int rf = 0; rf < 8; ++rf) {
#pragma unroll
    for (int r = 0; r < 4; ++r) {
      float v = tmin[rf][r];
      v = fminf(v, __shfl_xor(v, 1, 64));
      v = fminf(v, __shfl_xor(v, 2, 64));
      v = fminf(v, __shfl_xor(v, 4, 64));
      v = fminf(v, __shfl_xor(v, 8, 64));
      if (l15 == 0) minbuf[rf * 16 + q * 4 + r][w] = v;
    }
  }
  __syncthreads();

  if (w < 2) {  // rows 0..127: wave w covers rows w*64 + lane
    int row = w * 64 + lane;
    float m = fminf(fminf(minbuf[row][0], minbuf[row][1]),
                    fminf(minbuf[row][2], minbuf[row][3]));
    float t = m * rxs[row];                  // fold 1/(1-x2) once per row
    float arg = fmaxf(fmaf(2.f, t, 1.f), 1.f + EPS_F);
    float contrib = fmaxf(marg[0] - acoshf(arg), 0.f);
#pragma unroll
    for (int off = 32; off > 0; off >>= 1) contrib += __shfl_xor(contrib, off, 64);
    if (lane == 0) atomicAdd(out, contrib * (1.0f / 32768.f));
  }
}

// ---------------------------------------------------------------------------
extern "C" void kernel_launch(void* const* d_in, const int* in_sizes, int n_in,
                              void* d_out, int out_size, void* d_ws, size_t ws_size,
                              hipStream_t stream) {
  const float* z      = (const float*)d_in[0];  // 32768 x 512 fp32
  const float* protos = (const float*)d_in[1];  // 2048 x 512 fp32
  const float* marg   = (const float*)d_in[2];  // scalar
  float* out = (float*)d_out;
  uint8_t* wsB = (uint8_t*)d_ws;                // 1 MB image (lo/hi 512 KB planes)
  // 192 KB pad absorbs the harmless B-pipeline tail over-reads (<= 32 KB).
  float* y2a = (float*)((char*)d_ws + (1 << 20) + 192 * 1024);   // 8 KB
  float* rya = y2a + 2048;                                       // 8 KB

  prep_kernel<<<512, 256, 0, stream>>>(protos, wsB, y2a, rya, out);
  gemm_min_kernel<<<256, 256, 0, stream>>>(z, wsB, y2a, rya, marg, out);
}